// Round 1
// baseline (4646.114 us; speedup 1.0000x reference)
//
#include <hip/hip_runtime.h>

#define NN 50000
#define NE 800000
#define D 128
#define NG 128

// ---------------- degree count ----------------
__global__ void count_kernel(const int* __restrict__ dst, float* __restrict__ cnt, int E) {
    int e = blockIdx.x * blockDim.x + threadIdx.x;
    if (e < E) atomicAdd(&cnt[dst[e]], 1.0f);
}

__global__ void inv_kernel(const float* __restrict__ cnt, float* __restrict__ inv, int N) {
    int n = blockIdx.x * blockDim.x + threadIdx.x;
    if (n < N) inv[n] = 1.0f / fmaxf(cnt[n], 1.0f);
}

// ---------------- scatter-add msg = in[src] into agg[dst] ----------------
// thread = (edge, 4-float chunk); lanes of a wave cover contiguous columns of
// an edge's source row -> coalesced float4 gathers, 4 f32 atomics per thread.
__global__ void scatter_kernel(const float* __restrict__ in, const int* __restrict__ src,
                               const int* __restrict__ dst, float* __restrict__ agg, int E) {
    int gid = blockIdx.x * blockDim.x + threadIdx.x;
    int e = gid >> 5;
    if (e >= E) return;
    int c = (gid & 31) * 4;
    int s = src[e], d = dst[e];
    float4 v = *reinterpret_cast<const float4*>(in + (size_t)s * D + c);
    float* p = agg + (size_t)d * D + c;
    atomicAdd(p + 0, v.x);
    atomicAdd(p + 1, v.y);
    atomicAdd(p + 2, v.z);
    atomicAdd(p + 3, v.w);
}

// ---------------- fused SAGE transform: out = relu((agg*inv)@Wl + bl + in@Wr) ----------------
// 32 rows/block, 256 threads, each thread 4 rows x 4 cols register tile.
__global__ __launch_bounds__(256) void transform_kernel(
    const float* __restrict__ in, const float* __restrict__ agg,
    const float* __restrict__ inv, const float* __restrict__ Wl,
    const float* __restrict__ bl, const float* __restrict__ Wr,
    float* __restrict__ out, int N) {
    __shared__ float a[32][256];   // [row][0:128]=agg*inv, [128:256]=in
    const int tid = threadIdx.x;
    const int row0 = blockIdx.x * 32;

    const int qc = tid & 63;
    const int rsub = tid >> 6;
    for (int pass = 0; pass < 8; ++pass) {
        int r = pass * 4 + rsub;
        int n = row0 + r;
        if (n < N) {
            if (qc < 32) {
                float4 v = *reinterpret_cast<const float4*>(agg + (size_t)n * D + qc * 4);
                float s = inv[n];
                v.x *= s; v.y *= s; v.z *= s; v.w *= s;
                *reinterpret_cast<float4*>(&a[r][qc * 4]) = v;
            } else {
                float4 v = *reinterpret_cast<const float4*>(in + (size_t)n * D + (qc - 32) * 4);
                *reinterpret_cast<float4*>(&a[r][128 + (qc - 32) * 4]) = v;
            }
        }
    }
    __syncthreads();

    const int j0 = (tid & 31) * 4;
    const int r0 = (tid >> 5) * 4;
    float acc[4][4] = {};

    for (int k = 0; k < 128; ++k) {
        float4 w = *reinterpret_cast<const float4*>(Wl + k * D + j0);
#pragma unroll
        for (int i = 0; i < 4; ++i) {
            float av = a[r0 + i][k];
            acc[i][0] += av * w.x; acc[i][1] += av * w.y;
            acc[i][2] += av * w.z; acc[i][3] += av * w.w;
        }
    }
    for (int k = 0; k < 128; ++k) {
        float4 w = *reinterpret_cast<const float4*>(Wr + k * D + j0);
#pragma unroll
        for (int i = 0; i < 4; ++i) {
            float av = a[r0 + i][128 + k];
            acc[i][0] += av * w.x; acc[i][1] += av * w.y;
            acc[i][2] += av * w.z; acc[i][3] += av * w.w;
        }
    }

    float4 bias = *reinterpret_cast<const float4*>(bl + j0);
#pragma unroll
    for (int i = 0; i < 4; ++i) {
        int n = row0 + r0 + i;
        if (n < N) {
            float4 o;
            o.x = fmaxf(acc[i][0] + bias.x, 0.0f);
            o.y = fmaxf(acc[i][1] + bias.y, 0.0f);
            o.z = fmaxf(acc[i][2] + bias.z, 0.0f);
            o.w = fmaxf(acc[i][3] + bias.w, 0.0f);
            *reinterpret_cast<float4*>(out + (size_t)n * D + j0) = o;
        }
    }
}

// ---------------- global mean pool ----------------
__global__ void gcnt_kernel(const int* __restrict__ batch, float* __restrict__ gcnt, int N) {
    int n = blockIdx.x * blockDim.x + threadIdx.x;
    if (n < N) atomicAdd(&gcnt[batch[n]], 1.0f);
}

__global__ void pool_kernel(const float* __restrict__ h, const int* __restrict__ batch,
                            float* __restrict__ gsum, int N) {
    int gid = blockIdx.x * blockDim.x + threadIdx.x;
    int n = gid >> 5;
    if (n >= N) return;
    int c = (gid & 31) * 4;
    int b = batch[n];
    float4 v = *reinterpret_cast<const float4*>(h + (size_t)n * D + c);
    float* p = gsum + b * D + c;
    atomicAdd(p + 0, v.x);
    atomicAdd(p + 1, v.y);
    atomicAdd(p + 2, v.z);
    atomicAdd(p + 3, v.w);
}

// ---------------- head: relu(g@W1+b1) @ W2 + b2, log_softmax ----------------
__global__ __launch_bounds__(128) void head_kernel(
    const float* __restrict__ gsum, const float* __restrict__ gcnt,
    const float* __restrict__ W1, const float* __restrict__ b1,
    const float* __restrict__ W2, const float* __restrict__ b2,
    float* __restrict__ out) {
    __shared__ float gl[128];
    __shared__ float tl[128];
    __shared__ float lg[10];
    __shared__ float red[2];
    int b = blockIdx.x, j = threadIdx.x;

    float c = fmaxf(gcnt[b], 1.0f);
    gl[j] = gsum[b * D + j] / c;
    __syncthreads();

    float t = b1[j];
    for (int k = 0; k < 128; ++k) t += gl[k] * W1[k * 128 + j];
    tl[j] = fmaxf(t, 0.0f);
    __syncthreads();

    if (j < 10) {
        float acc = b2[j];
        for (int k = 0; k < 128; ++k) acc += tl[k] * W2[k * 10 + j];
        lg[j] = acc;
    }
    __syncthreads();

    if (j == 0) {
        float m = lg[0];
        for (int q = 1; q < 10; ++q) m = fmaxf(m, lg[q]);
        float s = 0.0f;
        for (int q = 0; q < 10; ++q) s += expf(lg[q] - m);
        red[0] = m;
        red[1] = logf(s);
    }
    __syncthreads();

    if (j < 10) out[b * 10 + j] = lg[j] - red[0] - red[1];
}

extern "C" void kernel_launch(void* const* d_in, const int* in_sizes, int n_in,
                              void* d_out, int out_size, void* d_ws, size_t ws_size,
                              hipStream_t stream) {
    const float* x    = (const float*)d_in[0];
    const int*   ei   = (const int*)d_in[1];
    const int*   src  = ei;
    const int*   dst  = ei + NE;
    const int*   batch = (const int*)d_in[2];
    const float* Wl1 = (const float*)d_in[3];
    const float* bl1 = (const float*)d_in[4];
    const float* Wr1 = (const float*)d_in[5];
    const float* Wl2 = (const float*)d_in[6];
    const float* bl2 = (const float*)d_in[7];
    const float* Wr2 = (const float*)d_in[8];
    const float* Wl3 = (const float*)d_in[9];
    const float* bl3 = (const float*)d_in[10];
    const float* Wr3 = (const float*)d_in[11];
    const float* W1  = (const float*)d_in[12];
    const float* b1  = (const float*)d_in[13];
    const float* W2  = (const float*)d_in[14];
    const float* b2  = (const float*)d_in[15];
    float* out = (float*)d_out;

    float* ws   = (float*)d_ws;
    float* agg  = ws;                         // 6,400,000
    float* hA   = ws + 6400000;               // 6,400,000
    float* hB   = ws + 12800000;              // 6,400,000
    float* cnt  = ws + 19200000;              // 50,000
    float* inv  = ws + 19250000;              // 50,000
    float* gsum = ws + 19300000;              // 16,384
    float* gcnt = ws + 19316384;              // 128

    // degree (same for all layers)
    hipMemsetAsync(cnt, 0, (size_t)NN * 4, stream);
    count_kernel<<<(NE + 255) / 256, 256, 0, stream>>>(dst, cnt, NE);
    inv_kernel<<<(NN + 255) / 256, 256, 0, stream>>>(cnt, inv, NN);

    const float* lin[3]  = { x, hA, hB };
    float*       lout[3] = { hA, hB, hA };
    const float* Wls[3] = { Wl1, Wl2, Wl3 };
    const float* bls[3] = { bl1, bl2, bl3 };
    const float* Wrs[3] = { Wr1, Wr2, Wr3 };

    const int scatter_blocks = (NE * 32) / 256;       // 100000
    const int trans_blocks = (NN + 31) / 32;          // 1563

    for (int L = 0; L < 3; ++L) {
        hipMemsetAsync(agg, 0, (size_t)NN * D * 4, stream);
        scatter_kernel<<<scatter_blocks, 256, 0, stream>>>(lin[L], src, dst, agg, NE);
        transform_kernel<<<trans_blocks, 256, 0, stream>>>(lin[L], agg, inv, Wls[L], bls[L], Wrs[L], lout[L], NN);
    }

    // pool over graphs
    hipMemsetAsync(gsum, 0, (size_t)(NG * D + NG) * 4, stream);
    gcnt_kernel<<<(NN + 255) / 256, 256, 0, stream>>>(batch, gcnt, NN);
    pool_kernel<<<(NN * 32) / 256, 256, 0, stream>>>(hA, batch, gsum, NN);

    head_kernel<<<NG, 128, 0, stream>>>(gsum, gcnt, W1, b1, W2, b2, out);
}

// Round 2
// 688.128 us; speedup vs baseline: 6.7518x; 6.7518x over previous
//
#include <hip/hip_runtime.h>

#define NN 50000
#define NE 800000
#define D 128
#define NG 128

// ---------------- degree histogram (int) ----------------
__global__ void count_kernel(const int* __restrict__ dst, int* __restrict__ cnt, int E) {
    int e = blockIdx.x * blockDim.x + threadIdx.x;
    if (e < E) atomicAdd(&cnt[dst[e]], 1);
}

__global__ void inv_kernel(const int* __restrict__ cnt, float* __restrict__ inv, int N) {
    int n = blockIdx.x * blockDim.x + threadIdx.x;
    if (n < N) inv[n] = 1.0f / fmaxf((float)cnt[n], 1.0f);
}

// ---------------- single-block exclusive scan: rowptr from cnt ----------------
__global__ __launch_bounds__(1024) void scan_kernel(const int* __restrict__ cnt,
                                                    int* __restrict__ rowptr, int N) {
    __shared__ int part[1024];
    const int t = threadIdx.x;
    const int chunk = (N + 1023) / 1024;
    const int base = t * chunk;
    int s = 0;
    for (int i = 0; i < chunk; ++i) {
        int idx = base + i;
        if (idx < N) s += cnt[idx];
    }
    part[t] = s;
    __syncthreads();
    // Hillis-Steele inclusive scan
    int val = s;
    for (int off = 1; off < 1024; off <<= 1) {
        int other = (t >= off) ? part[t - off] : 0;
        __syncthreads();
        val += other;
        part[t] = val;
        __syncthreads();
    }
    int run = val - s;   // exclusive prefix of this chunk
    for (int i = 0; i < chunk; ++i) {
        int idx = base + i;
        if (idx < N) { rowptr[idx] = run; run += cnt[idx]; }
    }
    if (t == 1023) rowptr[N] = run;   // total == E (last chunk is past N, s==0)
}

// ---------------- CSR fill: col[rowptr[d] + k] = src(e) ----------------
__global__ void fill_kernel(const int* __restrict__ src, const int* __restrict__ dst,
                            const int* __restrict__ rowptr, int* __restrict__ fill,
                            int* __restrict__ col, int E) {
    int e = blockIdx.x * blockDim.x + threadIdx.x;
    if (e < E) {
        int d = dst[e];
        int pos = atomicAdd(&fill[d], 1);
        col[rowptr[d] + pos] = src[e];
    }
}

// ---------------- CSR mean-aggregate: agg[n] = (1/deg) * sum_{e in row n} in[col[e]] ----------------
// one 64-lane wave per node; lane covers 2 columns (float2) -> 512B coalesced row gathers
__global__ __launch_bounds__(256) void aggregate_kernel(
    const float* __restrict__ in, const int* __restrict__ rowptr,
    const int* __restrict__ col, const float* __restrict__ inv,
    float* __restrict__ agg, int N) {
    int wid = (blockIdx.x * 256 + threadIdx.x) >> 6;
    int lane = threadIdx.x & 63;
    if (wid >= N) return;
    int lo = rowptr[wid], hi = rowptr[wid + 1];
    const int c = lane * 2;
    float ax = 0.0f, ay = 0.0f;
    int e = lo;
    for (; e + 1 < hi; e += 2) {
        int s0 = col[e], s1 = col[e + 1];
        float2 v0 = *reinterpret_cast<const float2*>(in + (size_t)s0 * D + c);
        float2 v1 = *reinterpret_cast<const float2*>(in + (size_t)s1 * D + c);
        ax += v0.x + v1.x;
        ay += v0.y + v1.y;
    }
    if (e < hi) {
        int s0 = col[e];
        float2 v0 = *reinterpret_cast<const float2*>(in + (size_t)s0 * D + c);
        ax += v0.x;
        ay += v0.y;
    }
    float sc = inv[wid];
    float2 o;
    o.x = ax * sc;
    o.y = ay * sc;
    *reinterpret_cast<float2*>(agg + (size_t)wid * D + c) = o;
}

// ---------------- fused SAGE transform: out = relu(agg@Wl + bl + in@Wr) ----------------
// 32 rows/block, 256 threads, each thread 4 rows x 4 cols register tile.
// NOTE: safe for out==in (each block reads only its own 32 rows, all before writes).
__global__ __launch_bounds__(256) void transform_kernel(
    const float* __restrict__ in, const float* __restrict__ agg,
    const float* __restrict__ Wl, const float* __restrict__ bl,
    const float* __restrict__ Wr, float* __restrict__ out, int N) {
    __shared__ float a[32][256];   // [row][0:128]=agg, [128:256]=in
    const int tid = threadIdx.x;
    const int row0 = blockIdx.x * 32;

    const int qc = tid & 63;
    const int rsub = tid >> 6;
    for (int pass = 0; pass < 8; ++pass) {
        int r = pass * 4 + rsub;
        int n = row0 + r;
        if (n < N) {
            if (qc < 32) {
                float4 v = *reinterpret_cast<const float4*>(agg + (size_t)n * D + qc * 4);
                *reinterpret_cast<float4*>(&a[r][qc * 4]) = v;
            } else {
                float4 v = *reinterpret_cast<const float4*>(in + (size_t)n * D + (qc - 32) * 4);
                *reinterpret_cast<float4*>(&a[r][128 + (qc - 32) * 4]) = v;
            }
        }
    }
    __syncthreads();

    const int j0 = (tid & 31) * 4;
    const int r0 = (tid >> 5) * 4;
    float acc[4][4] = {};

    for (int k = 0; k < 128; ++k) {
        float4 w = *reinterpret_cast<const float4*>(Wl + k * D + j0);
#pragma unroll
        for (int i = 0; i < 4; ++i) {
            float av = a[r0 + i][k];
            acc[i][0] += av * w.x; acc[i][1] += av * w.y;
            acc[i][2] += av * w.z; acc[i][3] += av * w.w;
        }
    }
    for (int k = 0; k < 128; ++k) {
        float4 w = *reinterpret_cast<const float4*>(Wr + k * D + j0);
#pragma unroll
        for (int i = 0; i < 4; ++i) {
            float av = a[r0 + i][128 + k];
            acc[i][0] += av * w.x; acc[i][1] += av * w.y;
            acc[i][2] += av * w.z; acc[i][3] += av * w.w;
        }
    }

    float4 bias = *reinterpret_cast<const float4*>(bl + j0);
#pragma unroll
    for (int i = 0; i < 4; ++i) {
        int n = row0 + r0 + i;
        if (n < N) {
            float4 o;
            o.x = fmaxf(acc[i][0] + bias.x, 0.0f);
            o.y = fmaxf(acc[i][1] + bias.y, 0.0f);
            o.z = fmaxf(acc[i][2] + bias.z, 0.0f);
            o.w = fmaxf(acc[i][3] + bias.w, 0.0f);
            *reinterpret_cast<float4*>(out + (size_t)n * D + j0) = o;
        }
    }
}

// ---------------- fused pool (sorted batch -> binary search) + MLP head + log_softmax ----------------
__global__ __launch_bounds__(128) void pool_head_kernel(
    const float* __restrict__ h, const int* __restrict__ batch, int N,
    const float* __restrict__ W1, const float* __restrict__ b1,
    const float* __restrict__ W2, const float* __restrict__ b2,
    float* __restrict__ out) {
    __shared__ float gl[128];
    __shared__ float tl[128];
    __shared__ float lg[10];
    __shared__ float red[2];
    const int b = blockIdx.x, j = threadIdx.x;

    // lower_bound(batch, b) and lower_bound(batch, b+1) — batch is sorted
    int lo = 0, r = N;
    while (lo < r) { int m = (lo + r) >> 1; if (batch[m] < b) lo = m + 1; else r = m; }
    int hi = lo; r = N;
    while (hi < r) { int m = (hi + r) >> 1; if (batch[m] < b + 1) hi = m + 1; else r = m; }

    float sum = 0.0f;
    for (int n = lo; n < hi; ++n) sum += h[(size_t)n * D + j];
    float c = fmaxf((float)(hi - lo), 1.0f);
    gl[j] = sum / c;
    __syncthreads();

    float t = b1[j];
    for (int k = 0; k < 128; ++k) t += gl[k] * W1[k * 128 + j];
    tl[j] = fmaxf(t, 0.0f);
    __syncthreads();

    if (j < 10) {
        float acc = b2[j];
        for (int k = 0; k < 128; ++k) acc += tl[k] * W2[k * 10 + j];
        lg[j] = acc;
    }
    __syncthreads();

    if (j == 0) {
        float m = lg[0];
        for (int q = 1; q < 10; ++q) m = fmaxf(m, lg[q]);
        float s = 0.0f;
        for (int q = 0; q < 10; ++q) s += expf(lg[q] - m);
        red[0] = m;
        red[1] = logf(s);
    }
    __syncthreads();

    if (j < 10) out[b * 10 + j] = lg[j] - red[0] - red[1];
}

extern "C" void kernel_launch(void* const* d_in, const int* in_sizes, int n_in,
                              void* d_out, int out_size, void* d_ws, size_t ws_size,
                              hipStream_t stream) {
    const float* x    = (const float*)d_in[0];
    const int*   ei   = (const int*)d_in[1];
    const int*   src  = ei;
    const int*   dst  = ei + NE;
    const int*   batch = (const int*)d_in[2];
    const float* Wl1 = (const float*)d_in[3];
    const float* bl1 = (const float*)d_in[4];
    const float* Wr1 = (const float*)d_in[5];
    const float* Wl2 = (const float*)d_in[6];
    const float* bl2 = (const float*)d_in[7];
    const float* Wr2 = (const float*)d_in[8];
    const float* Wl3 = (const float*)d_in[9];
    const float* bl3 = (const float*)d_in[10];
    const float* Wr3 = (const float*)d_in[11];
    const float* W1  = (const float*)d_in[12];
    const float* b1  = (const float*)d_in[13];
    const float* W2  = (const float*)d_in[14];
    const float* b2  = (const float*)d_in[15];
    float* out = (float*)d_out;

    float* ws   = (float*)d_ws;
    float* agg  = ws;                         // 6,400,000 floats
    float* hA   = ws + 6400000;               // 6,400,000 floats
    float* inv  = ws + 12800000;              // 50,000 floats
    int*   ib     = (int*)(ws + 12850000);
    int*   cnt    = ib;                       // 50,000 ints
    int*   rowptr = ib + 50000;               // 50,001 ints
    int*   fill   = ib + 100001;              // 50,000 ints
    int*   col    = ib + 150001;              // 800,000 ints
    // total ~55.2 MB (known ws_size >= 77 MB from round 1)

    // ---- CSR build (edge_index is constant across layers) ----
    hipMemsetAsync(cnt, 0, (size_t)NN * 4, stream);
    hipMemsetAsync(fill, 0, (size_t)NN * 4, stream);
    count_kernel<<<(NE + 255) / 256, 256, 0, stream>>>(dst, cnt, NE);
    inv_kernel<<<(NN + 255) / 256, 256, 0, stream>>>(cnt, inv, NN);
    scan_kernel<<<1, 1024, 0, stream>>>(cnt, rowptr, NN);
    fill_kernel<<<(NE + 255) / 256, 256, 0, stream>>>(src, dst, rowptr, fill, col, NE);

    const int agg_blocks = (NN * 64 + 255) / 256;     // one wave per node
    const int trans_blocks = (NN + 31) / 32;

    // L1: x -> hA
    aggregate_kernel<<<agg_blocks, 256, 0, stream>>>(x, rowptr, col, inv, agg, NN);
    transform_kernel<<<trans_blocks, 256, 0, stream>>>(x, agg, Wl1, bl1, Wr1, hA, NN);
    // L2: hA -> hA (in-place safe)
    aggregate_kernel<<<agg_blocks, 256, 0, stream>>>(hA, rowptr, col, inv, agg, NN);
    transform_kernel<<<trans_blocks, 256, 0, stream>>>(hA, agg, Wl2, bl2, Wr2, hA, NN);
    // L3: hA -> hA
    aggregate_kernel<<<agg_blocks, 256, 0, stream>>>(hA, rowptr, col, inv, agg, NN);
    transform_kernel<<<trans_blocks, 256, 0, stream>>>(hA, agg, Wl3, bl3, Wr3, hA, NN);

    pool_head_kernel<<<NG, 128, 0, stream>>>(hA, batch, NN, W1, b1, W2, b2, out);
}

// Round 3
// 615.107 us; speedup vs baseline: 7.5533x; 1.1187x over previous
//
#include <hip/hip_runtime.h>

#define NN 50000
#define NE 800000
#define D 128
#define NG 128
#define POOL_NODES 128

// ---------------- degree histogram (int) ----------------
__global__ void count_kernel(const int* __restrict__ dst, int* __restrict__ cnt, int E) {
    int e = blockIdx.x * blockDim.x + threadIdx.x;
    if (e < E) atomicAdd(&cnt[dst[e]], 1);
}

__global__ void inv_kernel(const int* __restrict__ cnt, float* __restrict__ inv, int N) {
    int n = blockIdx.x * blockDim.x + threadIdx.x;
    if (n < N) inv[n] = 1.0f / fmaxf((float)cnt[n], 1.0f);
}

// ---------------- single-block exclusive scan: rowptr from cnt ----------------
__global__ __launch_bounds__(1024) void scan_kernel(const int* __restrict__ cnt,
                                                    int* __restrict__ rowptr, int N) {
    __shared__ int part[1024];
    const int t = threadIdx.x;
    const int chunk = (N + 1023) / 1024;
    const int base = t * chunk;
    int s = 0;
    for (int i = 0; i < chunk; ++i) {
        int idx = base + i;
        if (idx < N) s += cnt[idx];
    }
    part[t] = s;
    __syncthreads();
    int val = s;
    for (int off = 1; off < 1024; off <<= 1) {
        int other = (t >= off) ? part[t - off] : 0;
        __syncthreads();
        val += other;
        part[t] = val;
        __syncthreads();
    }
    int run = val - s;
    for (int i = 0; i < chunk; ++i) {
        int idx = base + i;
        if (idx < N) { rowptr[idx] = run; run += cnt[idx]; }
    }
    if (t == 1023) rowptr[N] = run;
}

// ---------------- CSR fill ----------------
__global__ void fill_kernel(const int* __restrict__ src, const int* __restrict__ dst,
                            const int* __restrict__ rowptr, int* __restrict__ fill,
                            int* __restrict__ col, int E) {
    int e = blockIdx.x * blockDim.x + threadIdx.x;
    if (e < E) {
        int d = dst[e];
        int pos = atomicAdd(&fill[d], 1);
        col[rowptr[d] + pos] = src[e];
    }
}

// ---------------- CSR mean-aggregate ----------------
__global__ __launch_bounds__(256) void aggregate_kernel(
    const float* __restrict__ in, const int* __restrict__ rowptr,
    const int* __restrict__ col, const float* __restrict__ inv,
    float* __restrict__ agg, int N) {
    int wid = (blockIdx.x * 256 + threadIdx.x) >> 6;
    int lane = threadIdx.x & 63;
    if (wid >= N) return;
    int lo = rowptr[wid], hi = rowptr[wid + 1];
    const int c = lane * 2;
    float ax = 0.0f, ay = 0.0f;
    int e = lo;
    for (; e + 1 < hi; e += 2) {
        int s0 = col[e], s1 = col[e + 1];
        float2 v0 = *reinterpret_cast<const float2*>(in + (size_t)s0 * D + c);
        float2 v1 = *reinterpret_cast<const float2*>(in + (size_t)s1 * D + c);
        ax += v0.x + v1.x;
        ay += v0.y + v1.y;
    }
    if (e < hi) {
        int s0 = col[e];
        float2 v0 = *reinterpret_cast<const float2*>(in + (size_t)s0 * D + c);
        ax += v0.x;
        ay += v0.y;
    }
    float sc = inv[wid];
    float2 o;
    o.x = ax * sc;
    o.y = ay * sc;
    *reinterpret_cast<float2*>(agg + (size_t)wid * D + c) = o;
}

// ---------------- fused SAGE transform: out = relu(agg@Wl + bl + in@Wr) ----------------
__global__ __launch_bounds__(256) void transform_kernel(
    const float* __restrict__ in, const float* __restrict__ agg,
    const float* __restrict__ Wl, const float* __restrict__ bl,
    const float* __restrict__ Wr, float* __restrict__ out, int N) {
    __shared__ float a[32][256];   // [row][0:128]=agg, [128:256]=in
    const int tid = threadIdx.x;
    const int row0 = blockIdx.x * 32;

    const int qc = tid & 63;
    const int rsub = tid >> 6;
    for (int pass = 0; pass < 8; ++pass) {
        int r = pass * 4 + rsub;
        int n = row0 + r;
        if (n < N) {
            if (qc < 32) {
                float4 v = *reinterpret_cast<const float4*>(agg + (size_t)n * D + qc * 4);
                *reinterpret_cast<float4*>(&a[r][qc * 4]) = v;
            } else {
                float4 v = *reinterpret_cast<const float4*>(in + (size_t)n * D + (qc - 32) * 4);
                *reinterpret_cast<float4*>(&a[r][128 + (qc - 32) * 4]) = v;
            }
        }
    }
    __syncthreads();

    const int j0 = (tid & 31) * 4;
    const int r0 = (tid >> 5) * 4;
    float acc[4][4] = {};

    for (int k = 0; k < 128; ++k) {
        float4 w = *reinterpret_cast<const float4*>(Wl + k * D + j0);
#pragma unroll
        for (int i = 0; i < 4; ++i) {
            float av = a[r0 + i][k];
            acc[i][0] += av * w.x; acc[i][1] += av * w.y;
            acc[i][2] += av * w.z; acc[i][3] += av * w.w;
        }
    }
    for (int k = 0; k < 128; ++k) {
        float4 w = *reinterpret_cast<const float4*>(Wr + k * D + j0);
#pragma unroll
        for (int i = 0; i < 4; ++i) {
            float av = a[r0 + i][128 + k];
            acc[i][0] += av * w.x; acc[i][1] += av * w.y;
            acc[i][2] += av * w.z; acc[i][3] += av * w.w;
        }
    }

    float4 bias = *reinterpret_cast<const float4*>(bl + j0);
#pragma unroll
    for (int i = 0; i < 4; ++i) {
        int n = row0 + r0 + i;
        if (n < N) {
            float4 o;
            o.x = fmaxf(acc[i][0] + bias.x, 0.0f);
            o.y = fmaxf(acc[i][1] + bias.y, 0.0f);
            o.z = fmaxf(acc[i][2] + bias.z, 0.0f);
            o.w = fmaxf(acc[i][3] + bias.w, 0.0f);
            *reinterpret_cast<float4*>(out + (size_t)n * D + j0) = o;
        }
    }
}

// ---------------- parallel pool: chunked node sum -> atomic flush per graph run ----------------
__global__ __launch_bounds__(256) void pool_kernel(
    const float* __restrict__ h, const int* __restrict__ batch,
    float* __restrict__ gsum, int N) {
    const int c = (threadIdx.x & 63) * 2;
    const int r = threadIdx.x >> 6;           // 0..3
    const int n0 = blockIdx.x * POOL_NODES;
    const int n1 = min(n0 + POOL_NODES, N);
    int gid = -1;
    float ax = 0.0f, ay = 0.0f;
    for (int n = n0 + r; n < n1; n += 4) {
        int b = batch[n];
        if (b != gid) {
            if (gid >= 0) {
                atomicAdd(&gsum[gid * D + c], ax);
                atomicAdd(&gsum[gid * D + c + 1], ay);
            }
            gid = b; ax = 0.0f; ay = 0.0f;
        }
        float2 v = *reinterpret_cast<const float2*>(h + (size_t)n * D + c);
        ax += v.x; ay += v.y;
    }
    if (gid >= 0) {
        atomicAdd(&gsum[gid * D + c], ax);
        atomicAdd(&gsum[gid * D + c + 1], ay);
    }
}

// ---------------- head: mean -> relu(g@W1+b1) @ W2 + b2 -> log_softmax ----------------
__global__ __launch_bounds__(128) void head_kernel(
    const float* __restrict__ gsum, const int* __restrict__ batch, int N,
    const float* __restrict__ W1, const float* __restrict__ b1,
    const float* __restrict__ W2, const float* __restrict__ b2,
    float* __restrict__ out) {
    __shared__ float gl[128];
    __shared__ float tl[128];
    __shared__ float lg[10];
    __shared__ float red[2];
    const int b = blockIdx.x, j = threadIdx.x;

    // node count for graph b via binary search (batch sorted)
    int lo = 0, r = N;
    while (lo < r) { int m = (lo + r) >> 1; if (batch[m] < b) lo = m + 1; else r = m; }
    int hi = lo; r = N;
    while (hi < r) { int m = (hi + r) >> 1; if (batch[m] < b + 1) hi = m + 1; else r = m; }

    float c = fmaxf((float)(hi - lo), 1.0f);
    gl[j] = gsum[b * D + j] / c;
    __syncthreads();

    float t = b1[j];
    for (int k = 0; k < 128; ++k) t += gl[k] * W1[k * 128 + j];
    tl[j] = fmaxf(t, 0.0f);
    __syncthreads();

    if (j < 10) {
        float acc = b2[j];
        for (int k = 0; k < 128; ++k) acc += tl[k] * W2[k * 10 + j];
        lg[j] = acc;
    }
    __syncthreads();

    if (j == 0) {
        float m = lg[0];
        for (int q = 1; q < 10; ++q) m = fmaxf(m, lg[q]);
        float s = 0.0f;
        for (int q = 0; q < 10; ++q) s += expf(lg[q] - m);
        red[0] = m;
        red[1] = logf(s);
    }
    __syncthreads();

    if (j < 10) out[b * 10 + j] = lg[j] - red[0] - red[1];
}

extern "C" void kernel_launch(void* const* d_in, const int* in_sizes, int n_in,
                              void* d_out, int out_size, void* d_ws, size_t ws_size,
                              hipStream_t stream) {
    const float* x    = (const float*)d_in[0];
    const int*   ei   = (const int*)d_in[1];
    const int*   src  = ei;
    const int*   dst  = ei + NE;
    const int*   batch = (const int*)d_in[2];
    const float* Wl1 = (const float*)d_in[3];
    const float* bl1 = (const float*)d_in[4];
    const float* Wr1 = (const float*)d_in[5];
    const float* Wl2 = (const float*)d_in[6];
    const float* bl2 = (const float*)d_in[7];
    const float* Wr2 = (const float*)d_in[8];
    const float* Wl3 = (const float*)d_in[9];
    const float* bl3 = (const float*)d_in[10];
    const float* Wr3 = (const float*)d_in[11];
    const float* W1  = (const float*)d_in[12];
    const float* b1  = (const float*)d_in[13];
    const float* W2  = (const float*)d_in[14];
    const float* b2  = (const float*)d_in[15];
    float* out = (float*)d_out;

    float* ws   = (float*)d_ws;
    float* agg  = ws;                         // 6,400,000 floats
    float* hA   = ws + 6400000;               // 6,400,000 floats
    float* inv  = ws + 12800000;              // 50,000 floats
    float* gsum = ws + 12850000;              // 16,384 floats
    int*   ib     = (int*)(ws + 12866384);
    int*   cnt    = ib;                       // 50,000 ints
    int*   rowptr = ib + 50000;               // 50,001 ints
    int*   fill   = ib + 100001;              // 50,000 ints
    int*   col    = ib + 150001;              // 800,000 ints

    // ---- CSR build ----
    hipMemsetAsync(cnt, 0, (size_t)NN * 4, stream);
    hipMemsetAsync(fill, 0, (size_t)NN * 4, stream);
    hipMemsetAsync(gsum, 0, (size_t)NG * D * 4, stream);
    count_kernel<<<(NE + 255) / 256, 256, 0, stream>>>(dst, cnt, NE);
    inv_kernel<<<(NN + 255) / 256, 256, 0, stream>>>(cnt, inv, NN);
    scan_kernel<<<1, 1024, 0, stream>>>(cnt, rowptr, NN);
    fill_kernel<<<(NE + 255) / 256, 256, 0, stream>>>(src, dst, rowptr, fill, col, NE);

    const int agg_blocks = (NN * 64 + 255) / 256;
    const int trans_blocks = (NN + 31) / 32;

    aggregate_kernel<<<agg_blocks, 256, 0, stream>>>(x, rowptr, col, inv, agg, NN);
    transform_kernel<<<trans_blocks, 256, 0, stream>>>(x, agg, Wl1, bl1, Wr1, hA, NN);
    aggregate_kernel<<<agg_blocks, 256, 0, stream>>>(hA, rowptr, col, inv, agg, NN);
    transform_kernel<<<trans_blocks, 256, 0, stream>>>(hA, agg, Wl2, bl2, Wr2, hA, NN);
    aggregate_kernel<<<agg_blocks, 256, 0, stream>>>(hA, rowptr, col, inv, agg, NN);
    transform_kernel<<<trans_blocks, 256, 0, stream>>>(hA, agg, Wl3, bl3, Wr3, hA, NN);

    pool_kernel<<<(NN + POOL_NODES - 1) / POOL_NODES, 256, 0, stream>>>(hA, batch, gsum, NN);
    head_kernel<<<NG, 128, 0, stream>>>(gsum, batch, NN, W1, b1, W2, b2, out);
}

// Round 6
// 520.112 us; speedup vs baseline: 8.9329x; 1.1826x over previous
//
#include <hip/hip_runtime.h>

#define NN 50000
#define NE 800000
#define D 128
#define NG 128
#define POOL_NODES 128
#define SCAN_NB ((NN + 1023) / 1024)   // 49

// ---------------- degree histogram (int) ----------------
__global__ void count_kernel(const int* __restrict__ dst, int* __restrict__ cnt, int E) {
    int e = blockIdx.x * blockDim.x + threadIdx.x;
    if (e < E) atomicAdd(&cnt[dst[e]], 1);
}

__global__ void inv_kernel(const int* __restrict__ cnt, float* __restrict__ inv, int N) {
    int n = blockIdx.x * blockDim.x + threadIdx.x;
    if (n < N) inv[n] = 1.0f / fmaxf((float)cnt[n], 1.0f);
}

// ---------------- multi-block scan, phase 1: per-block (1024 ints) sums ----------------
__global__ __launch_bounds__(256) void blocksum_kernel(const int* __restrict__ cnt,
                                                       int* __restrict__ bsum, int N) {
    int base = blockIdx.x * 1024 + threadIdx.x * 4;
    int s = 0;
    if (base + 3 < N) {
        int4 v = *reinterpret_cast<const int4*>(cnt + base);
        s = v.x + v.y + v.z + v.w;
    } else {
        for (int i = 0; i < 4; ++i) if (base + i < N) s += cnt[base + i];
    }
    for (int off = 32; off > 0; off >>= 1) s += __shfl_down(s, off, 64);
    __shared__ int wsum[4];
    if ((threadIdx.x & 63) == 0) wsum[threadIdx.x >> 6] = s;
    __syncthreads();
    if (threadIdx.x == 0) bsum[blockIdx.x] = wsum[0] + wsum[1] + wsum[2] + wsum[3];
}

// ---------------- phase 2: one wave scans the NB block sums (inclusive, in place) ----------------
__global__ void scansum_kernel(int* __restrict__ bsum, int* __restrict__ rowptr, int NB, int N) {
    int t = threadIdx.x;
    int v = (t < NB) ? bsum[t] : 0;
    for (int off = 1; off < 64; off <<= 1) {
        int u = __shfl_up(v, off, 64);
        if (t >= off) v += u;
    }
    if (t < NB) bsum[t] = v;
    if (t == NB - 1) rowptr[N] = v;   // total == E
}

// ---------------- phase 3: write exclusive rowptr ----------------
__global__ __launch_bounds__(256) void writeptr_kernel(const int* __restrict__ cnt,
                                                       const int* __restrict__ bsum,
                                                       int* __restrict__ rowptr, int N) {
    const int b = blockIdx.x;
    const int base = b * 1024 + threadIdx.x * 4;
    int vals[4];
#pragma unroll
    for (int i = 0; i < 4; ++i) vals[i] = (base + i < N) ? cnt[base + i] : 0;
    int s = vals[0] + vals[1] + vals[2] + vals[3];

    const int lane = threadIdx.x & 63, w = threadIdx.x >> 6;
    int incl = s;
    for (int off = 1; off < 64; off <<= 1) {
        int u = __shfl_up(incl, off, 64);
        if (lane >= off) incl += u;
    }
    __shared__ int wsum[4];
    if (lane == 63) wsum[w] = incl;
    __syncthreads();
    int excl = (b == 0) ? 0 : bsum[b - 1];
    for (int i = 0; i < w; ++i) excl += wsum[i];
    excl += incl - s;

    int run = excl;
#pragma unroll
    for (int i = 0; i < 4; ++i) {
        if (base + i < N) { rowptr[base + i] = run; run += vals[i]; }
    }
}

// ---------------- CSR fill ----------------
__global__ void fill_kernel(const int* __restrict__ src, const int* __restrict__ dst,
                            const int* __restrict__ rowptr, int* __restrict__ fill,
                            int* __restrict__ col, int E) {
    int e = blockIdx.x * blockDim.x + threadIdx.x;
    if (e < E) {
        int d = dst[e];
        int pos = atomicAdd(&fill[d], 1);
        col[rowptr[d] + pos] = src[e];
    }
}

// ---------------- CSR mean-aggregate ----------------
__global__ __launch_bounds__(256) void aggregate_kernel(
    const float* __restrict__ in, const int* __restrict__ rowptr,
    const int* __restrict__ col, const float* __restrict__ inv,
    float* __restrict__ agg, int N) {
    int wid = (blockIdx.x * 256 + threadIdx.x) >> 6;
    int lane = threadIdx.x & 63;
    if (wid >= N) return;
    int lo = rowptr[wid], hi = rowptr[wid + 1];
    const int c = lane * 2;
    float ax = 0.0f, ay = 0.0f;
    int e = lo;
    for (; e + 1 < hi; e += 2) {
        int s0 = col[e], s1 = col[e + 1];
        float2 v0 = *reinterpret_cast<const float2*>(in + (size_t)s0 * D + c);
        float2 v1 = *reinterpret_cast<const float2*>(in + (size_t)s1 * D + c);
        ax += v0.x + v1.x;
        ay += v0.y + v1.y;
    }
    if (e < hi) {
        int s0 = col[e];
        float2 v0 = *reinterpret_cast<const float2*>(in + (size_t)s0 * D + c);
        ax += v0.x;
        ay += v0.y;
    }
    float sc = inv[wid];
    float2 o;
    o.x = ax * sc;
    o.y = ay * sc;
    *reinterpret_cast<float2*>(agg + (size_t)wid * D + c) = o;
}

// ---------------- fused SAGE transform: out = relu(agg@Wl + bl + in@Wr) ----------------
__global__ __launch_bounds__(256) void transform_kernel(
    const float* __restrict__ in, const float* __restrict__ agg,
    const float* __restrict__ Wl, const float* __restrict__ bl,
    const float* __restrict__ Wr, float* __restrict__ out, int N) {
    __shared__ float a[32][256];   // [row][0:128]=agg, [128:256]=in
    const int tid = threadIdx.x;
    const int row0 = blockIdx.x * 32;

    const int qc = tid & 63;
    const int rsub = tid >> 6;
    for (int pass = 0; pass < 8; ++pass) {
        int r = pass * 4 + rsub;
        int n = row0 + r;
        if (n < N) {
            if (qc < 32) {
                float4 v = *reinterpret_cast<const float4*>(agg + (size_t)n * D + qc * 4);
                *reinterpret_cast<float4*>(&a[r][qc * 4]) = v;
            } else {
                float4 v = *reinterpret_cast<const float4*>(in + (size_t)n * D + (qc - 32) * 4);
                *reinterpret_cast<float4*>(&a[r][128 + (qc - 32) * 4]) = v;
            }
        }
    }
    __syncthreads();

    const int j0 = (tid & 31) * 4;
    const int r0 = (tid >> 5) * 4;
    float acc[4][4] = {};

    for (int k = 0; k < 128; ++k) {
        float4 w = *reinterpret_cast<const float4*>(Wl + k * D + j0);
#pragma unroll
        for (int i = 0; i < 4; ++i) {
            float av = a[r0 + i][k];
            acc[i][0] += av * w.x; acc[i][1] += av * w.y;
            acc[i][2] += av * w.z; acc[i][3] += av * w.w;
        }
    }
    for (int k = 0; k < 128; ++k) {
        float4 w = *reinterpret_cast<const float4*>(Wr + k * D + j0);
#pragma unroll
        for (int i = 0; i < 4; ++i) {
            float av = a[r0 + i][128 + k];
            acc[i][0] += av * w.x; acc[i][1] += av * w.y;
            acc[i][2] += av * w.z; acc[i][3] += av * w.w;
        }
    }

    float4 bias = *reinterpret_cast<const float4*>(bl + j0);
#pragma unroll
    for (int i = 0; i < 4; ++i) {
        int n = row0 + r0 + i;
        if (n < N) {
            float4 o;
            o.x = fmaxf(acc[i][0] + bias.x, 0.0f);
            o.y = fmaxf(acc[i][1] + bias.y, 0.0f);
            o.z = fmaxf(acc[i][2] + bias.z, 0.0f);
            o.w = fmaxf(acc[i][3] + bias.w, 0.0f);
            *reinterpret_cast<float4*>(out + (size_t)n * D + j0) = o;
        }
    }
}

// ---------------- parallel pool: chunked node sum -> atomic flush per graph run ----------------
__global__ __launch_bounds__(256) void pool_kernel(
    const float* __restrict__ h, const int* __restrict__ batch,
    float* __restrict__ gsum, int N) {
    const int c = (threadIdx.x & 63) * 2;
    const int r = threadIdx.x >> 6;           // 0..3
    const int n0 = blockIdx.x * POOL_NODES;
    const int n1 = min(n0 + POOL_NODES, N);
    int gid = -1;
    float ax = 0.0f, ay = 0.0f;
    for (int n = n0 + r; n < n1; n += 4) {
        int b = batch[n];
        if (b != gid) {
            if (gid >= 0) {
                atomicAdd(&gsum[gid * D + c], ax);
                atomicAdd(&gsum[gid * D + c + 1], ay);
            }
            gid = b; ax = 0.0f; ay = 0.0f;
        }
        float2 v = *reinterpret_cast<const float2*>(h + (size_t)n * D + c);
        ax += v.x; ay += v.y;
    }
    if (gid >= 0) {
        atomicAdd(&gsum[gid * D + c], ax);
        atomicAdd(&gsum[gid * D + c + 1], ay);
    }
}

// ---------------- head: mean -> relu(g@W1+b1) @ W2 + b2 -> log_softmax ----------------
__global__ __launch_bounds__(128) void head_kernel(
    const float* __restrict__ gsum, const int* __restrict__ batch, int N,
    const float* __restrict__ W1, const float* __restrict__ b1,
    const float* __restrict__ W2, const float* __restrict__ b2,
    float* __restrict__ out) {
    __shared__ float gl[128];
    __shared__ float tl[128];
    __shared__ float lg[10];
    __shared__ float red[2];
    const int b = blockIdx.x, j = threadIdx.x;

    int lo = 0, r = N;
    while (lo < r) { int m = (lo + r) >> 1; if (batch[m] < b) lo = m + 1; else r = m; }
    int hi = lo; r = N;
    while (hi < r) { int m = (hi + r) >> 1; if (batch[m] < b + 1) hi = m + 1; else r = m; }

    float c = fmaxf((float)(hi - lo), 1.0f);
    gl[j] = gsum[b * D + j] / c;
    __syncthreads();

    float t = b1[j];
    for (int k = 0; k < 128; ++k) t += gl[k] * W1[k * 128 + j];
    tl[j] = fmaxf(t, 0.0f);
    __syncthreads();

    if (j < 10) {
        float acc = b2[j];
        for (int k = 0; k < 128; ++k) acc += tl[k] * W2[k * 10 + j];
        lg[j] = acc;
    }
    __syncthreads();

    if (j == 0) {
        float m = lg[0];
        for (int q = 1; q < 10; ++q) m = fmaxf(m, lg[q]);
        float s = 0.0f;
        for (int q = 0; q < 10; ++q) s += expf(lg[q] - m);
        red[0] = m;
        red[1] = logf(s);
    }
    __syncthreads();

    if (j < 10) out[b * 10 + j] = lg[j] - red[0] - red[1];
}

extern "C" void kernel_launch(void* const* d_in, const int* in_sizes, int n_in,
                              void* d_out, int out_size, void* d_ws, size_t ws_size,
                              hipStream_t stream) {
    const float* x    = (const float*)d_in[0];
    const int*   ei   = (const int*)d_in[1];
    const int*   src  = ei;
    const int*   dst  = ei + NE;
    const int*   batch = (const int*)d_in[2];
    const float* Wl1 = (const float*)d_in[3];
    const float* bl1 = (const float*)d_in[4];
    const float* Wr1 = (const float*)d_in[5];
    const float* Wl2 = (const float*)d_in[6];
    const float* bl2 = (const float*)d_in[7];
    const float* Wr2 = (const float*)d_in[8];
    const float* Wl3 = (const float*)d_in[9];
    const float* bl3 = (const float*)d_in[10];
    const float* Wr3 = (const float*)d_in[11];
    const float* W1  = (const float*)d_in[12];
    const float* b1  = (const float*)d_in[13];
    const float* W2  = (const float*)d_in[14];
    const float* b2  = (const float*)d_in[15];
    float* out = (float*)d_out;

    float* ws   = (float*)d_ws;
    float* agg  = ws;                         // 6,400,000 floats
    float* hA   = ws + 6400000;               // 6,400,000 floats
    float* inv  = ws + 12800000;              // 50,000 floats
    float* gsum = ws + 12850000;              // 16,384 floats
    int*   ib     = (int*)(ws + 12866384);
    int*   cnt    = ib;                       // 50,000 ints
    int*   rowptr = ib + 50000;               // 50,001 ints
    int*   fill   = ib + 100001;              // 50,000 ints
    int*   col    = ib + 150001;              // 800,000 ints
    int*   bsum   = ib + 950001;              // 64 ints

    // ---- CSR build ----
    hipMemsetAsync(cnt, 0, (size_t)NN * 4, stream);
    hipMemsetAsync(fill, 0, (size_t)NN * 4, stream);
    hipMemsetAsync(gsum, 0, (size_t)NG * D * 4, stream);
    count_kernel<<<(NE + 255) / 256, 256, 0, stream>>>(dst, cnt, NE);
    inv_kernel<<<(NN + 255) / 256, 256, 0, stream>>>(cnt, inv, NN);
    blocksum_kernel<<<SCAN_NB, 256, 0, stream>>>(cnt, bsum, NN);
    scansum_kernel<<<1, 64, 0, stream>>>(bsum, rowptr, SCAN_NB, NN);
    writeptr_kernel<<<SCAN_NB, 256, 0, stream>>>(cnt, bsum, rowptr, NN);
    fill_kernel<<<(NE + 255) / 256, 256, 0, stream>>>(src, dst, rowptr, fill, col, NE);

    const int agg_blocks = (NN * 64 + 255) / 256;
    const int trans_blocks = (NN + 31) / 32;

    aggregate_kernel<<<agg_blocks, 256, 0, stream>>>(x, rowptr, col, inv, agg, NN);
    transform_kernel<<<trans_blocks, 256, 0, stream>>>(x, agg, Wl1, bl1, Wr1, hA, NN);
    aggregate_kernel<<<agg_blocks, 256, 0, stream>>>(hA, rowptr, col, inv, agg, NN);
    transform_kernel<<<trans_blocks, 256, 0, stream>>>(hA, agg, Wl2, bl2, Wr2, hA, NN);
    aggregate_kernel<<<agg_blocks, 256, 0, stream>>>(hA, rowptr, col, inv, agg, NN);
    transform_kernel<<<trans_blocks, 256, 0, stream>>>(hA, agg, Wl3, bl3, Wr3, hA, NN);

    pool_kernel<<<(NN + POOL_NODES - 1) / POOL_NODES, 256, 0, stream>>>(hA, batch, gsum, NN);
    head_kernel<<<NG, 128, 0, stream>>>(gsum, batch, NN, W1, b1, W2, b2, out);
}